// Round 1
// baseline (679.179 us; speedup 1.0000x reference)
//
#include <hip/hip_runtime.h>
#include <hip/hip_bf16.h>
#include <math.h>

// Problem constants (from reference)
#define IN_C  16
#define OUT_C 64
#define HH    256
#define WW    256
#define OHH   254
#define OWW   254
#define NB    32

#define P    8   // vertical pixels per thread (consecutive oh)
#define OCH  8   // output channels per accumulation chunk

// Fused: Conv2d(16->64,3x3,VALID) + bias -> min over oc -> tanh(tanh(.))
// fp32 direct conv. VALU-bound by design (no fp32-input MFMA on CDNA4);
// this is the correctness-anchored baseline before the bf16 MFMA rewrite.
__global__ __launch_bounds__(256, 2)
void conv_min_tanh_f32(const float* __restrict__ x,
                       const float* __restrict__ w,
                       const float* __restrict__ bias,
                       float* __restrict__ out)
{
    // Weights re-laid-out: lds_w[(c*3+kh)*3+kw][oc] -> 8 consecutive oc = 32B,
    // read as broadcast (same addr all lanes, conflict-free ds_read_b128 pairs).
    __shared__ float lds_w[IN_C * 9 * OUT_C];  // 36.9 KB
    const int tid = threadIdx.x;
    for (int i = tid; i < OUT_C * IN_C * 9; i += 256) {
        const int oc = i / (IN_C * 9);
        const int r  = i - oc * (IN_C * 9);   // (c*3+kh)*3+kw
        lds_w[r * OUT_C + oc] = w[i];
    }
    __syncthreads();

    const int ow  = tid;                 // 0..255 (254..255 masked at store)
    const int oh0 = blockIdx.x * P;      // vertical tile base
    const int n   = blockIdx.y;
    const int owc = ow < OWW ? ow : (OWW - 1);   // clamp for safe loads
    const float* xn = x + (size_t)n * IN_C * HH * WW;

    float minv[P];
#pragma unroll
    for (int p = 0; p < P; ++p) minv[p] = INFINITY;

    // 8 chunks of 8 output channels; acc[8][8] = 64 VGPRs.
    for (int chunk = 0; chunk < OUT_C / OCH; ++chunk) {
        float acc[OCH][P];
#pragma unroll
        for (int o = 0; o < OCH; ++o) {
            const float b = bias[chunk * OCH + o];   // uniform -> s_load
#pragma unroll
            for (int p = 0; p < P; ++p) acc[o][p] = b;
        }

        for (int c = 0; c < IN_C; ++c) {
            // x patch: rows oh0..oh0+P+1 (clamped), cols owc..owc+2
            float xv[P + 2][3];
#pragma unroll
            for (int r = 0; r < P + 2; ++r) {
                int row = oh0 + r; if (row > HH - 1) row = HH - 1;
                const float* xp = xn + ((size_t)c * HH + row) * WW + owc;
                xv[r][0] = xp[0]; xv[r][1] = xp[1]; xv[r][2] = xp[2];
            }
#pragma unroll
            for (int kh = 0; kh < 3; ++kh) {
#pragma unroll
                for (int kw = 0; kw < 3; ++kw) {
                    const float* wp = &lds_w[((c * 3 + kh) * 3 + kw) * OUT_C + chunk * OCH];
                    float wv[OCH];
#pragma unroll
                    for (int o = 0; o < OCH; ++o) wv[o] = wp[o];
#pragma unroll
                    for (int o = 0; o < OCH; ++o) {
#pragma unroll
                        for (int p = 0; p < P; ++p)
                            acc[o][p] = fmaf(xv[p + kh][kw], wv[o], acc[o][p]);
                    }
                }
            }
        }
#pragma unroll
        for (int o = 0; o < OCH; ++o)
#pragma unroll
            for (int p = 0; p < P; ++p)
                minv[p] = fminf(minv[p], acc[o][p]);
    }

    if (ow < OWW) {
#pragma unroll
        for (int p = 0; p < P; ++p) {
            const int oh = oh0 + p;
            if (oh < OHH) {
                out[((size_t)n * OHH + oh) * OWW + ow] = tanhf(tanhf(minv[p]));
            }
        }
    }
}

extern "C" void kernel_launch(void* const* d_in, const int* in_sizes, int n_in,
                              void* d_out, int out_size, void* d_ws, size_t ws_size,
                              hipStream_t stream)
{
    const float* x = (const float*)d_in[0];
    const float* w = (const float*)d_in[1];
    const float* b = (const float*)d_in[2];
    float* out     = (float*)d_out;

    dim3 grid((OHH + P - 1) / P, NB);   // (32, 32) = 1024 blocks
    conv_min_tanh_f32<<<grid, 256, 0, stream>>>(x, w, b, out);
}

// Round 2
// 295.602 us; speedup vs baseline: 2.2976x; 2.2976x over previous
//
#include <hip/hip_runtime.h>
#include <math.h>

// Fused Conv2d(16->64,3x3,VALID) + bias -> min(oc) -> tanh(tanh()) on MI355X.
// Implicit-GEMM via v_mfma_f32_32x32x16_bf16 with split-bf16 (hi/lo) operands
// for fp32-class accuracy: y = xh*wh + xl*wh + xh*wl (missing xl*wl ~ 2^-18).
// A-operand = weights (registers, rows = 32 oc), B-operand = pixels (LDS,
// cols = 32 output columns), K = 16 input channels = one 3x3 tap.
// Bias folded as a 10th tap: A=[bias_hi,bias_lo,0..], B=[1,1,0..].

#define IN_C  16
#define OUT_C 64
#define HH    256
#define WW    256
#define OHH   254
#define OWW   254
#define NB    32

#define TH 16      // output rows per block
#define TW 32      // output cols per block (= MFMA N)
#define HR (TH + 2) // 18 halo rows staged
#define HC 36       // halo cols staged (34 needed, 36 for float4 staging)

typedef __attribute__((ext_vector_type(8)))  short short8;    // 8 bf16
typedef __attribute__((ext_vector_type(16))) float floatx16;  // 16 f32 acc
typedef __attribute__((ext_vector_type(4)))  float float4v;

__device__ __forceinline__ unsigned short f2bf(float f) {
    unsigned u = __float_as_uint(f);
    u = u + 0x7FFFu + ((u >> 16) & 1u);          // round-to-nearest-even
    return (unsigned short)(u >> 16);
}
__device__ __forceinline__ float bf2f(unsigned short h) {
    return __uint_as_float(((unsigned)h) << 16);
}

// LDS x layout: cell(r, col) = 64B = 4 slots of 16B: s = part*2 + cblk,
// part 0=hi 1=lo, cblk = c/8. Slot index XOR-swizzled by col and row so the
// 64-lane ds_read_b128 fragment read (lanes = cols, stride 64B) is
// conflict-free (2-way worst case, free per m136).
__device__ __forceinline__ int slot_addr(int rh, int colh, int s) {
    const int m = (colh & 3) ^ ((colh >> 2) & 3) ^ (rh & 3);
    return (rh * HC + colh) * 64 + ((s ^ m) << 4);
}

__global__ __launch_bounds__(256, 2)
void conv_min_tanh_mfma(const float* __restrict__ x,
                        const float* __restrict__ w,
                        const float* __restrict__ bias,
                        float* __restrict__ out)
{
    __shared__ unsigned char lds_x[HR * HC * 64];   // 41472 B
    __shared__ float comb[2][TH][TW];               // 4096 B

    const int tid  = threadIdx.x;
    const int lane = tid & 63;
    const int wave = tid >> 6;

    const int bx      = blockIdx.x;      // 0..127
    const int coltile = bx & 7;
    const int rowtile = bx >> 3;
    const int n       = blockIdx.y;
    const int oh0     = rowtile * TH;
    const int ow0     = coltile * TW;

    const float* xn = x + (size_t)n * IN_C * HH * WW;

    // ---- stage x tile: fp32 global -> bf16 hi/lo in swizzled LDS ----
    // 16 c * 18 r * 9 float4 quads = 2592 vector loads, q fastest for
    // intra-wave coalescing runs.
    for (int i = tid; i < IN_C * HR * 9; i += 256) {
        const int c   = i / (HR * 9);
        const int rem = i - c * (HR * 9);
        const int r   = rem / 9;
        const int q   = rem - r * 9;
        const int gr  = min(oh0 + r, HH - 1);       // clamp bottom halo
        int gc = ow0 + q * 4;
        if (gc > WW - 4) gc = WW - 4;               // clamp right halo (tile 7)
        const float4v v = *(const float4v*)(xn + (c * HH + gr) * WW + gc);
        const int cblk = c >> 3;
        const int coff = (c & 7) * 2;
#pragma unroll
        for (int j = 0; j < 4; ++j) {
            const int colh = q * 4 + j;             // 0..35
            const float f = v[j];
            const unsigned short h = f2bf(f);
            const unsigned short l = f2bf(f - bf2f(h));
            *(unsigned short*)(lds_x + slot_addr(r, colh, cblk) + coff)     = h;
            *(unsigned short*)(lds_x + slot_addr(r, colh, 2 + cblk) + coff) = l;
        }
    }

    // ---- build A (weight) fragments in registers, hi/lo split ----
    // A[row=oc][k=c]: lane holds oc = l&31, c = 8*(l>>5) + j.
    const int octile = wave & 1;                    // waves 0,1: rows 0-7; 2,3: 8-15
    const int rbase  = (wave >> 1) * (TH / 2);
    const int oc     = octile * 32 + (lane & 31);
    const int cblk8  = (lane >> 5) * 8;

    short8 whi[9], wlo[9];
#pragma unroll
    for (int t = 0; t < 9; ++t) {
        const int kh = t / 3, kw = t % 3;
#pragma unroll
        for (int j = 0; j < 8; ++j) {
            const int c = cblk8 + j;
            const float wv = w[((oc * IN_C + c) * 3 + kh) * 3 + kw];
            const unsigned short h = f2bf(wv);
            whi[t][j] = (short)h;
            wlo[t][j] = (short)f2bf(wv - bf2f(h));
        }
    }
    // bias tap: A k=0 -> bias_hi, k=1 -> bias_lo; B "ones" k=0,1 -> 1.0bf16
    short8 wb   = {};
    short8 ones = {};
    if (lane < 32) {                                // lanes <32 hold k=0..7
        const float bv = bias[oc];
        const unsigned short h = f2bf(bv);
        wb[0]   = (short)h;
        wb[1]   = (short)f2bf(bv - bf2f(h));
        ones[0] = (short)0x3F80;
        ones[1] = (short)0x3F80;
    }

    __syncthreads();

    // ---- per-output-row MFMA loop ----
    // B[k=c][n=col]: lane reads 8 bf16 (one slot) at col = l&31 (+kw),
    // cblk = l>>5. Two accs (A/B) alternate per tap to break dep chains.
    const int colb = lane & 31;
    const int cblk = lane >> 5;
    for (int rr = 0; rr < TH / 2; ++rr) {
        const int rl = rbase + rr;                  // output row in tile
        floatx16 accA = {};
        floatx16 accB = {};
#pragma unroll
        for (int t = 0; t < 9; ++t) {
            const int kh = t / 3, kw = t % 3;
            const int rh   = rl + kh;               // 0..17
            const int colh = colb + kw;             // 0..33
            const short8 bhi = *(const short8*)(lds_x + slot_addr(rh, colh, cblk));
            const short8 blo = *(const short8*)(lds_x + slot_addr(rh, colh, 2 + cblk));
            if (t & 1) {
                accB = __builtin_amdgcn_mfma_f32_32x32x16_bf16(whi[t], bhi, accB, 0, 0, 0);
                accA = __builtin_amdgcn_mfma_f32_32x32x16_bf16(whi[t], blo, accA, 0, 0, 0);
                accB = __builtin_amdgcn_mfma_f32_32x32x16_bf16(wlo[t], bhi, accB, 0, 0, 0);
            } else {
                accA = __builtin_amdgcn_mfma_f32_32x32x16_bf16(whi[t], bhi, accA, 0, 0, 0);
                accB = __builtin_amdgcn_mfma_f32_32x32x16_bf16(whi[t], blo, accB, 0, 0, 0);
                accA = __builtin_amdgcn_mfma_f32_32x32x16_bf16(wlo[t], bhi, accA, 0, 0, 0);
            }
        }
        accA = __builtin_amdgcn_mfma_f32_32x32x16_bf16(wb, ones, accA, 0, 0, 0);

        // min over this wave's 32 ocs: 16 in-lane rows + partner half-wave
        float mv = accA[0] + accB[0];
#pragma unroll
        for (int i2 = 1; i2 < 16; ++i2) mv = fminf(mv, accA[i2] + accB[i2]);
        mv = fminf(mv, __shfl_xor(mv, 32, 64));
        if (lane < 32) comb[octile][rl][lane] = mv;
    }

    __syncthreads();

    // ---- combine the two oc-tiles, tanh(tanh()), masked store ----
    for (int i = tid; i < TH * TW; i += 256) {
        const int row  = i >> 5;
        const int colp = i & 31;
        const int oh = oh0 + row;
        const int ow = ow0 + colp;
        if (oh < OHH && ow < OWW) {
            float v = fminf(comb[0][row][colp], comb[1][row][colp]);
            v = tanhf(tanhf(v));
            out[((size_t)n * OHH + oh) * OWW + ow] = v;
        }
    }
}

extern "C" void kernel_launch(void* const* d_in, const int* in_sizes, int n_in,
                              void* d_out, int out_size, void* d_ws, size_t ws_size,
                              hipStream_t stream)
{
    const float* x = (const float*)d_in[0];
    const float* w = (const float*)d_in[1];
    const float* b = (const float*)d_in[2];
    float* out     = (float*)d_out;

    dim3 grid(128, NB);   // 16 row-tiles * 8 col-tiles, 32 batches
    conv_min_tanh_mfma<<<grid, 256, 0, stream>>>(x, w, b, out);
}

// Round 3
// 277.380 us; speedup vs baseline: 2.4485x; 1.0657x over previous
//
#include <hip/hip_runtime.h>
#include <math.h>

// Fused Conv2d(16->64,3x3,VALID)+bias -> min(oc) -> tanh(tanh()) via
// v_mfma_f32_32x32x16_bf16 with split-bf16 (hi/lo) operands:
// y = xh*wh + xl*wh + xh*wl (+bias tap). A=weights(reg), B=pixels(LDS).
// R3: vectorized b128 staging (was 2-byte scalar writes = 18.9M bank
// conflicts), full-period XOR swizzle, TH=12 for 3-4 blocks/CU overlap.

#define IN_C  16
#define OUT_C 64
#define HH    256
#define WW    256
#define OHH   254
#define OWW   254
#define NB    32

#define TH 12       // output rows per block
#define TW 32       // output cols per block (= MFMA N)
#define HR (TH + 2) // 14 halo rows staged
#define HC 34       // halo cols staged

typedef __attribute__((ext_vector_type(8)))  short short8;    // 8 bf16
typedef __attribute__((ext_vector_type(16))) float floatx16;  // 16 f32 acc

__device__ __forceinline__ unsigned short f2bf(float f) {   // RNE
    unsigned u = __float_as_uint(f);
    u = u + 0x7FFFu + ((u >> 16) & 1u);
    return (unsigned short)(u >> 16);
}
__device__ __forceinline__ float bf2f(unsigned short h) {
    return __uint_as_float(((unsigned)h) << 16);
}

// LDS cell(r,col) = 64B = 4 slots of 16B: slot 0=hi c0-7, 1=hi c8-15,
// 2=lo c0-7, 3=lo c8-15. Physical slot = s ^ m, m full-period in col
// (bits 0..5) and row, so both the 64-lane b128 fragment reads (lanes =
// cols at 64B stride) and the staging b128 writes are conflict-free.
__device__ __forceinline__ int slot_addr(int rh, int colh, int s) {
    const int m = (colh ^ (colh >> 2) ^ (colh >> 4) ^ rh) & 3;
    return (rh * HC + colh) * 64 + ((s ^ m) << 4);
}

// tanh(tanh(v)) via fast exp; exact saturation at +-inf.
__device__ __forceinline__ float tanh2_fast(float v) {
    const float e1 = __expf(2.0f * v);
    const float t1 = 1.0f - 2.0f / (e1 + 1.0f);
    const float e2 = __expf(2.0f * t1);
    return 1.0f - 2.0f / (e2 + 1.0f);
}

__global__ __launch_bounds__(256, 3)
void conv_min_tanh_mfma2(const float* __restrict__ x,
                         const float* __restrict__ w,
                         const float* __restrict__ bias,
                         float* __restrict__ out)
{
    __shared__ __align__(64) unsigned char lds_x[HR * HC * 64];  // 30464 B
    __shared__ float comb[2][TH][TW];                            // 3072 B

    const int tid  = threadIdx.x;
    const int lane = tid & 63;
    const int wave = tid >> 6;

    const int bx      = blockIdx.x;      // 0..175
    const int coltile = bx & 7;
    const int rowtile = bx >> 3;         // 0..21
    const int n       = blockIdx.y;
    const int oh0     = rowtile * TH;
    const int ow0     = coltile * TW;

    const float* xn = x + (size_t)n * IN_C * HH * WW;

    // ---- stage x tile: per item (r,col) load all 16 channels, split to
    // bf16 hi(trunc)/lo(RNE of exact residual), write 4 x ds_write_b128 ----
    for (int i = tid; i < HR * HC; i += 256) {
        const int r    = i / HC;
        const int colh = i - r * HC;
        const int gr = min(oh0 + r, HH - 1);      // clamp bottom halo
        const int gc = min(ow0 + colh, WW - 1);   // clamp right halo
        const float* xp = xn + gr * WW + gc;
        unsigned u[IN_C];
#pragma unroll
        for (int c = 0; c < IN_C; ++c) u[c] = __float_as_uint(xp[c * (HH * WW)]);
        short8 s0, s1, s2, s3;
#pragma unroll
        for (int j = 0; j < 8; ++j) {
            const unsigned ua = u[j], ub = u[j + 8];
            s0[j] = (short)(ua >> 16);            // hi = truncate
            s1[j] = (short)(ub >> 16);
            s2[j] = (short)f2bf(__uint_as_float(ua) - __uint_as_float(ua & 0xFFFF0000u));
            s3[j] = (short)f2bf(__uint_as_float(ub) - __uint_as_float(ub & 0xFFFF0000u));
        }
        *(short8*)(lds_x + slot_addr(r, colh, 0)) = s0;
        *(short8*)(lds_x + slot_addr(r, colh, 1)) = s1;
        *(short8*)(lds_x + slot_addr(r, colh, 2)) = s2;
        *(short8*)(lds_x + slot_addr(r, colh, 3)) = s3;
    }

    // ---- A (weight) fragments, hi/lo split: lane holds oc=l&31, c=8*(l>>5)+j
    const int octile = wave & 1;                 // waves 0,1: oc 0-31 / 32-63
    const int rbase  = (wave >> 1) * (TH / 2);   // waves 0,1: rows 0-5; 2,3: 6-11
    const int oc     = octile * 32 + (lane & 31);
    const int cblk8  = (lane >> 5) * 8;

    short8 whi[9], wlo[9];
#pragma unroll
    for (int t = 0; t < 9; ++t) {
        const int kh = t / 3, kw = t % 3;
#pragma unroll
        for (int j = 0; j < 8; ++j) {
            const int c = cblk8 + j;
            const float wv = w[((oc * IN_C + c) * 3 + kh) * 3 + kw];
            const unsigned short h = f2bf(wv);
            whi[t][j] = (short)h;
            wlo[t][j] = (short)f2bf(wv - bf2f(h));
        }
    }
    // bias tap: A k=0 -> bias_hi, k=1 -> bias_lo; B ones k=0,1 -> 1.0
    short8 wb = {}, ones = {};
    if (lane < 32) {
        const float bv = bias[oc];
        const unsigned short h = f2bf(bv);
        wb[0]   = (short)h;
        wb[1]   = (short)f2bf(bv - bf2f(h));
        ones[0] = (short)0x3F80;
        ones[1] = (short)0x3F80;
    }

    __syncthreads();

    // ---- MFMA loop: B[k=c][n=col], lane reads one 16B slot at col l&31(+kw)
    const int colb = lane & 31;
    const int cblk = lane >> 5;
    for (int rr = 0; rr < TH / 2; ++rr) {
        const int rl = rbase + rr;
        floatx16 accA = {}, accB = {};
#pragma unroll
        for (int t = 0; t < 9; ++t) {
            const int kh = t / 3, kw = t % 3;
            const int rh   = rl + kh;
            const int colh = colb + kw;
            const short8 bhi = *(const short8*)(lds_x + slot_addr(rh, colh, cblk));
            const short8 blo = *(const short8*)(lds_x + slot_addr(rh, colh, 2 + cblk));
            if (t & 1) {
                accB = __builtin_amdgcn_mfma_f32_32x32x16_bf16(whi[t], bhi, accB, 0, 0, 0);
                accA = __builtin_amdgcn_mfma_f32_32x32x16_bf16(whi[t], blo, accA, 0, 0, 0);
                accB = __builtin_amdgcn_mfma_f32_32x32x16_bf16(wlo[t], bhi, accB, 0, 0, 0);
            } else {
                accA = __builtin_amdgcn_mfma_f32_32x32x16_bf16(whi[t], bhi, accA, 0, 0, 0);
                accB = __builtin_amdgcn_mfma_f32_32x32x16_bf16(whi[t], blo, accB, 0, 0, 0);
                accA = __builtin_amdgcn_mfma_f32_32x32x16_bf16(wlo[t], bhi, accA, 0, 0, 0);
            }
        }
        accA = __builtin_amdgcn_mfma_f32_32x32x16_bf16(wb, ones, accA, 0, 0, 0);

        // min over this wave's 32 ocs: 16 in-lane rows + partner half-wave
        float mv = accA[0] + accB[0];
#pragma unroll
        for (int i2 = 1; i2 < 16; ++i2) mv = fminf(mv, accA[i2] + accB[i2]);
        mv = fminf(mv, __shfl_xor(mv, 32, 64));
        if (lane < 32) comb[octile][rl][lane] = mv;
    }

    __syncthreads();

    // ---- combine oc-tiles, tanh(tanh()), masked store ----
    for (int i = tid; i < TH * TW; i += 256) {
        const int row  = i >> 5;
        const int colp = i & 31;
        const int oh = oh0 + row;
        const int ow = ow0 + colp;
        if (oh < OHH && ow < OWW) {
            out[((size_t)n * OHH + oh) * OWW + ow] =
                tanh2_fast(fminf(comb[0][row][colp], comb[1][row][colp]));
        }
    }
}

extern "C" void kernel_launch(void* const* d_in, const int* in_sizes, int n_in,
                              void* d_out, int out_size, void* d_ws, size_t ws_size,
                              hipStream_t stream)
{
    const float* x = (const float*)d_in[0];
    const float* w = (const float*)d_in[1];
    const float* b = (const float*)d_in[2];
    float* out     = (float*)d_out;

    dim3 grid(22 * 8, NB);   // 22 row-tiles (ceil(254/12)) * 8 col-tiles, 32 batches
    conv_min_tanh_mfma2<<<grid, 256, 0, stream>>>(x, w, b, out);
}

// Round 6
// 255.708 us; speedup vs baseline: 2.6561x; 1.0848x over previous
//
#include <hip/hip_runtime.h>
#include <math.h>

// Fused Conv2d(16->64,3x3,VALID)+bias -> min(oc) -> tanh(tanh()) via
// v_mfma_f32_32x32x16_bf16, split-bf16 (hi/lo): y = xh*wh + xl*wh + xh*wl.
// R4: (1) weights pre-split into d_ws by a tiny pre-kernel (kills 144
// scalar loads + ~650 VALU per thread per block), (2) row-free period-16
// XOR swizzle + precomputed per-thread read offsets (addressing ~10 VALU/rr,
// reads provably conflict-free), (3) single acc chain.

#define IN_C  16
#define OUT_C 64
#define HH    256
#define WW    256
#define OHH   254
#define OWW   254
#define NB    32

#define TH 12       // output rows per block
#define TW 32       // output cols per block (= MFMA N)
#define HR (TH + 2) // halo rows staged
#define HC 34       // halo cols staged
#define ROWB (HC * 64)   // 2176 B per LDS row

typedef __attribute__((ext_vector_type(8)))  short short8;    // 8 bf16
typedef __attribute__((ext_vector_type(16))) float floatx16;  // 16 f32 acc

__device__ __forceinline__ unsigned short f2bf(float f) {   // RNE
    unsigned u = __float_as_uint(f);
    u = u + 0x7FFFu + ((u >> 16) & 1u);
    return (unsigned short)(u >> 16);
}
__device__ __forceinline__ float bf2f(unsigned short h) {
    return __uint_as_float(((unsigned)h) << 16);
}

// LDS cell(r,col) = 64B = 4 slots of 16B: logical slot 0=hi c0-7, 1=hi c8-15,
// 2=lo c0-7, 3=lo c8-15; physical slot = s ^ mc, mc period-16 in col only
// (uniform over any 32-consecutive-col window -> conflict-free b128 reads).
__device__ __forceinline__ int swz(int colh) {
    return (colh ^ (colh >> 2)) & 3;
}
__device__ __forceinline__ int slot_addr(int r, int colh, int s) {
    return r * ROWB + colh * 64 + ((s ^ swz(colh)) << 4);
}

// tanh(tanh(v)) via fast exp; saturates correctly at +-large.
__device__ __forceinline__ float tanh2_fast(float v) {
    const float e1 = __expf(2.0f * v);
    const float t1 = 1.0f - 2.0f / (e1 + 1.0f);
    const float e2 = __expf(2.0f * t1);
    return 1.0f - 2.0f / (e2 + 1.0f);
}

// ---- pre-kernel: split weights/bias to MFMA-fragment order in d_ws ----
// HI frags: ws[(oct*10 + t)*64 + lane], t=0..8 taps, t=9 = bias tap.
// LO frags: ws[1280 + (oct*9 + t)*64 + lane], t=0..8.
// Lane layout (A-operand, 32x32x16): oc = oct*32 + (lane&31), c = 8*(lane>>5)+j.
__global__ void split_weights(const float* __restrict__ w,
                              const float* __restrict__ bias,
                              short8* __restrict__ ws)
{
    const int tid = threadIdx.x;
    if (tid >= 128) return;
    const int oct  = tid >> 6;
    const int lane = tid & 63;
    const int oc   = oct * 32 + (lane & 31);
    const int cb   = (lane >> 5) * 8;
#pragma unroll
    for (int t = 0; t < 9; ++t) {
        const int kh = t / 3, kw = t % 3;
        short8 hi, lo;
#pragma unroll
        for (int j = 0; j < 8; ++j) {
            const float wv = w[((oc * IN_C + cb + j) * 3 + kh) * 3 + kw];
            const unsigned short h = f2bf(wv);
            hi[j] = (short)h;
            lo[j] = (short)f2bf(wv - bf2f(h));
        }
        ws[(oct * 10 + t) * 64 + lane]        = hi;
        ws[1280 + (oct * 9 + t) * 64 + lane]  = lo;
    }
    short8 wb = {};
    if (lane < 32) {
        const float bv = bias[oc];
        const unsigned short h = f2bf(bv);
        wb[0] = (short)h;
        wb[1] = (short)f2bf(bv - bf2f(h));
    }
    ws[(oct * 10 + 9) * 64 + lane] = wb;
}

__global__ __launch_bounds__(256, 3)
void conv_min_tanh_mfma3(const float* __restrict__ x,
                         const short8* __restrict__ ws,
                         float* __restrict__ out)
{
    __shared__ __align__(64) unsigned char lds_x[HR * ROWB];   // 30464 B
    __shared__ float comb[2][TH][TW];                          // 3072 B

    const int tid  = threadIdx.x;
    const int lane = tid & 63;
    const int wave = tid >> 6;

    const int bx      = blockIdx.x;      // 0..175
    const int coltile = bx & 7;
    const int rowtile = bx >> 3;         // 0..21
    const int n       = blockIdx.y;
    const int oh0     = rowtile * TH;
    const int ow0     = coltile * TW;

    const float* xn = x + (size_t)n * IN_C * HH * WW;

    // ---- weight fragments from d_ws (L2-resident, fragment-ordered) ----
    const int oct   = wave & 1;                  // waves 0,1: oc 0-31 / 32-63
    const int rbase = (wave >> 1) * (TH / 2);    // waves 0,1: rows 0-5; 2,3: 6-11
    short8 whi[10], wlo[9];
#pragma unroll
    for (int t = 0; t < 10; ++t) whi[t] = ws[(oct * 10 + t) * 64 + lane];
#pragma unroll
    for (int t = 0; t < 9; ++t)  wlo[t] = ws[1280 + (oct * 9 + t) * 64 + lane];
    short8 ones = {};
    if (lane < 32) { ones[0] = (short)0x3F80; ones[1] = (short)0x3F80; }

    // ---- stage x tile: load 16 channels per (r,col), split hi(trunc)/lo,
    // 4 conflict-free ds_write_b128 per item ----
    for (int i = tid; i < HR * HC; i += 256) {
        const int r    = i / HC;
        const int colh = i - r * HC;
        const int gr = min(oh0 + r, HH - 1);      // clamp bottom halo
        const int gc = min(ow0 + colh, WW - 1);   // clamp right halo
        const float* xp = xn + gr * WW + gc;
        unsigned u[IN_C];
#pragma unroll
        for (int c = 0; c < IN_C; ++c) u[c] = __float_as_uint(xp[c * (HH * WW)]);
        short8 s0, s1, s2, s3;
#pragma unroll
        for (int j = 0; j < 8; ++j) {
            const unsigned ua = u[j], ub = u[j + 8];
            s0[j] = (short)(ua >> 16);            // hi = truncate
            s1[j] = (short)(ub >> 16);
            s2[j] = (short)f2bf(__uint_as_float(ua) - __uint_as_float(ua & 0xFFFF0000u));
            s3[j] = (short)f2bf(__uint_as_float(ub) - __uint_as_float(ub & 0xFFFF0000u));
        }
        *(short8*)(lds_x + slot_addr(r, colh, 0)) = s0;
        *(short8*)(lds_x + slot_addr(r, colh, 1)) = s1;
        *(short8*)(lds_x + slot_addr(r, colh, 2)) = s2;
        *(short8*)(lds_x + slot_addr(r, colh, 3)) = s3;
    }

    __syncthreads();

    // ---- MFMA loop. Per-thread read offsets precomputed; inner addr =
    // rowoff + kh*ROWB + off[kw] (kh*ROWB folds to ds offset immediates).
    const int colb = lane & 31;
    const int cblk = lane >> 5;
    int offH[3], offL[3];
#pragma unroll
    for (int kw = 0; kw < 3; ++kw) {
        const int colh = colb + kw;
        const int m = swz(colh);
        offH[kw] = colh * 64 + ((cblk ^ m) << 4);
        offL[kw] = colh * 64 + (((2 + cblk) ^ m) << 4);
    }

    int rowoff = rbase * ROWB;
    for (int rr = 0; rr < TH / 2; ++rr) {
        floatx16 acc = {};
#pragma unroll
        for (int t = 0; t < 9; ++t) {
            const int kh = t / 3, kw = t % 3;
            const unsigned char* p = lds_x + rowoff + kh * ROWB;
            const short8 bhi = *(const short8*)(p + offH[kw]);
            const short8 blo = *(const short8*)(p + offL[kw]);
            acc = __builtin_amdgcn_mfma_f32_32x32x16_bf16(whi[t], bhi, acc, 0, 0, 0);
            acc = __builtin_amdgcn_mfma_f32_32x32x16_bf16(wlo[t], bhi, acc, 0, 0, 0);
            acc = __builtin_amdgcn_mfma_f32_32x32x16_bf16(whi[t], blo, acc, 0, 0, 0);
        }
        acc = __builtin_amdgcn_mfma_f32_32x32x16_bf16(whi[9], ones, acc, 0, 0, 0);

        // min over 16 in-lane oc rows (tree), then partner half-wave
        float m0 = fminf(acc[0],  acc[1]),  m1 = fminf(acc[2],  acc[3]);
        float m2 = fminf(acc[4],  acc[5]),  m3 = fminf(acc[6],  acc[7]);
        float m4 = fminf(acc[8],  acc[9]),  m5 = fminf(acc[10], acc[11]);
        float m6 = fminf(acc[12], acc[13]), m7 = fminf(acc[14], acc[15]);
        m0 = fminf(m0, m1); m2 = fminf(m2, m3); m4 = fminf(m4, m5); m6 = fminf(m6, m7);
        m0 = fminf(m0, m2); m4 = fminf(m4, m6);
        float mv = fminf(m0, m4);
        mv = fminf(mv, __shfl_xor(mv, 32, 64));
        if (lane < 32) comb[oct][rbase + rr][lane] = mv;
        rowoff += ROWB;
    }

    __syncthreads();

    // ---- combine oc-tiles, tanh(tanh()), masked store ----
    for (int i = tid; i < TH * TW; i += 256) {
        const int row  = i >> 5;
        const int colp = i & 31;
        const int oh = oh0 + row;
        const int ow = ow0 + colp;
        if (oh < OHH && ow < OWW) {
            out[((size_t)n * OHH + oh) * OWW + ow] =
                tanh2_fast(fminf(comb[0][row][colp], comb[1][row][colp]));
        }
    }
}

extern "C" void kernel_launch(void* const* d_in, const int* in_sizes, int n_in,
                              void* d_out, int out_size, void* d_ws, size_t ws_size,
                              hipStream_t stream)
{
    const float* x = (const float*)d_in[0];
    const float* w = (const float*)d_in[1];
    const float* b = (const float*)d_in[2];
    float* out     = (float*)d_out;
    short8* ws     = (short8*)d_ws;   // 38912 B used

    split_weights<<<1, 128, 0, stream>>>(w, b, ws);
    dim3 grid(22 * 8, NB);   // 22 row-tiles * 8 col-tiles, 32 batches
    conv_min_tanh_mfma3<<<grid, 256, 0, stream>>>(x, ws, out);
}

// Round 7
// 255.394 us; speedup vs baseline: 2.6593x; 1.0012x over previous
//
#include <hip/hip_runtime.h>
#include <math.h>

// Fused Conv2d(16->64,3x3,VALID)+bias -> min(oc) -> tanh(tanh()) via
// v_mfma_f32_32x32x16_bf16, split-bf16 (hi/lo): y = xh*wh + xl*wh + xh*wl.
// R7: row-ring reuse of hi B-fragments (rhi[3][3] register ring, rows
// shared across consecutive output rows) — LDS reads drop 18 -> 12 per rr,
// putting the LDS pipe (~3.7K cy/block) under the MFMA pipe (~5.4K cy/block).
// Everything else identical to R6 (110 us, MfmaUtil 52.5%).

#define IN_C  16
#define OUT_C 64
#define HH    256
#define WW    256
#define OHH   254
#define OWW   254
#define NB    32

#define TH 12       // output rows per block
#define TW 32       // output cols per block (= MFMA N)
#define HR (TH + 2) // halo rows staged
#define HC 34       // halo cols staged
#define ROWB (HC * 64)   // 2176 B per LDS row

typedef __attribute__((ext_vector_type(8)))  short short8;    // 8 bf16
typedef __attribute__((ext_vector_type(16))) float floatx16;  // 16 f32 acc

__device__ __forceinline__ unsigned short f2bf(float f) {   // RNE
    unsigned u = __float_as_uint(f);
    u = u + 0x7FFFu + ((u >> 16) & 1u);
    return (unsigned short)(u >> 16);
}
__device__ __forceinline__ float bf2f(unsigned short h) {
    return __uint_as_float(((unsigned)h) << 16);
}

// LDS cell(r,col) = 64B = 4 slots of 16B: logical slot 0=hi c0-7, 1=hi c8-15,
// 2=lo c0-7, 3=lo c8-15; physical slot = s ^ mc, mc period-16 in col only
// (uniform over any 32-consecutive-col window -> conflict-free b128 reads).
__device__ __forceinline__ int swz(int colh) {
    return (colh ^ (colh >> 2)) & 3;
}
__device__ __forceinline__ int slot_addr(int r, int colh, int s) {
    return r * ROWB + colh * 64 + ((s ^ swz(colh)) << 4);
}

// tanh(tanh(v)) via fast exp; saturates correctly at +-large.
__device__ __forceinline__ float tanh2_fast(float v) {
    const float e1 = __expf(2.0f * v);
    const float t1 = 1.0f - 2.0f / (e1 + 1.0f);
    const float e2 = __expf(2.0f * t1);
    return 1.0f - 2.0f / (e2 + 1.0f);
}

// ---- pre-kernel: split weights/bias to MFMA-fragment order in d_ws ----
// HI frags: ws[(oct*10 + t)*64 + lane], t=0..8 taps, t=9 = bias tap.
// LO frags: ws[1280 + (oct*9 + t)*64 + lane], t=0..8.
// Lane layout (A-operand, 32x32x16): oc = oct*32 + (lane&31), c = 8*(lane>>5)+j.
__global__ void split_weights(const float* __restrict__ w,
                              const float* __restrict__ bias,
                              short8* __restrict__ ws)
{
    const int tid = threadIdx.x;
    if (tid >= 128) return;
    const int oct  = tid >> 6;
    const int lane = tid & 63;
    const int oc   = oct * 32 + (lane & 31);
    const int cb   = (lane >> 5) * 8;
#pragma unroll
    for (int t = 0; t < 9; ++t) {
        const int kh = t / 3, kw = t % 3;
        short8 hi, lo;
#pragma unroll
        for (int j = 0; j < 8; ++j) {
            const float wv = w[((oc * IN_C + cb + j) * 3 + kh) * 3 + kw];
            const unsigned short h = f2bf(wv);
            hi[j] = (short)h;
            lo[j] = (short)f2bf(wv - bf2f(h));
        }
        ws[(oct * 10 + t) * 64 + lane]        = hi;
        ws[1280 + (oct * 9 + t) * 64 + lane]  = lo;
    }
    short8 wb = {};
    if (lane < 32) {
        const float bv = bias[oc];
        const unsigned short h = f2bf(bv);
        wb[0] = (short)h;
        wb[1] = (short)f2bf(bv - bf2f(h));
    }
    ws[(oct * 10 + 9) * 64 + lane] = wb;
}

__global__ __launch_bounds__(256, 3)
void conv_min_tanh_mfma4(const float* __restrict__ x,
                         const short8* __restrict__ ws,
                         float* __restrict__ out)
{
    __shared__ __align__(64) unsigned char lds_x[HR * ROWB];   // 30464 B
    __shared__ float comb[2][TH][TW];                          // 3072 B

    const int tid  = threadIdx.x;
    const int lane = tid & 63;
    const int wave = tid >> 6;

    const int bx      = blockIdx.x;      // 0..175
    const int coltile = bx & 7;
    const int rowtile = bx >> 3;         // 0..21
    const int n       = blockIdx.y;
    const int oh0     = rowtile * TH;
    const int ow0     = coltile * TW;

    const float* xn = x + (size_t)n * IN_C * HH * WW;

    // ---- weight fragments from d_ws (L2-resident, fragment-ordered) ----
    const int oct   = wave & 1;                  // waves 0,1: oc 0-31 / 32-63
    const int rbase = (wave >> 1) * (TH / 2);    // waves 0,1: rows 0-5; 2,3: 6-11
    short8 whi[10], wlo[9];
#pragma unroll
    for (int t = 0; t < 10; ++t) whi[t] = ws[(oct * 10 + t) * 64 + lane];
#pragma unroll
    for (int t = 0; t < 9; ++t)  wlo[t] = ws[1280 + (oct * 9 + t) * 64 + lane];
    short8 ones = {};
    if (lane < 32) { ones[0] = (short)0x3F80; ones[1] = (short)0x3F80; }

    // ---- stage x tile: load 16 channels per (r,col), split hi(trunc)/lo,
    // 4 conflict-free ds_write_b128 per item ----
    for (int i = tid; i < HR * HC; i += 256) {
        const int r    = i / HC;
        const int colh = i - r * HC;
        const int gr = min(oh0 + r, HH - 1);      // clamp bottom halo
        const int gc = min(ow0 + colh, WW - 1);   // clamp right halo
        const float* xp = xn + gr * WW + gc;
        unsigned u[IN_C];
#pragma unroll
        for (int c = 0; c < IN_C; ++c) u[c] = __float_as_uint(xp[c * (HH * WW)]);
        short8 s0, s1, s2, s3;
#pragma unroll
        for (int j = 0; j < 8; ++j) {
            const unsigned ua = u[j], ub = u[j + 8];
            s0[j] = (short)(ua >> 16);            // hi = truncate
            s1[j] = (short)(ub >> 16);
            s2[j] = (short)f2bf(__uint_as_float(ua) - __uint_as_float(ua & 0xFFFF0000u));
            s3[j] = (short)f2bf(__uint_as_float(ub) - __uint_as_float(ub & 0xFFFF0000u));
        }
        *(short8*)(lds_x + slot_addr(r, colh, 0)) = s0;
        *(short8*)(lds_x + slot_addr(r, colh, 1)) = s1;
        *(short8*)(lds_x + slot_addr(r, colh, 2)) = s2;
        *(short8*)(lds_x + slot_addr(r, colh, 3)) = s3;
    }

    __syncthreads();

    // ---- MFMA loop with hi-row register ring.
    // Relative row j (= rbase + j) lives in ring slot j%3; after full unroll
    // all ring indices are compile-time (no scratch, rule #20).
    const int colb = lane & 31;
    const int cblk = lane >> 5;
    int offH[3], offL[3];
#pragma unroll
    for (int kw = 0; kw < 3; ++kw) {
        const int colh = colb + kw;
        const int m = swz(colh);
        offH[kw] = colh * 64 + ((cblk ^ m) << 4);
        offL[kw] = colh * 64 + (((2 + cblk) ^ m) << 4);
    }

    const unsigned char* base = lds_x + rbase * ROWB;

    short8 rhi[3][3];   // [row%3][kw] hi fragments, 36 VGPR
#pragma unroll
    for (int j = 0; j < 2; ++j)
#pragma unroll
        for (int kw = 0; kw < 3; ++kw)
            rhi[j][kw] = *(const short8*)(base + j * ROWB + offH[kw]);

#pragma unroll
    for (int rr = 0; rr < TH / 2; ++rr) {
        // bring in row rr+2 (slot (rr+2)%3 held row rr-1, now dead)
#pragma unroll
        for (int kw = 0; kw < 3; ++kw)
            rhi[(rr + 2) % 3][kw] = *(const short8*)(base + (rr + 2) * ROWB + offH[kw]);

        floatx16 acc = {};
#pragma unroll
        for (int t = 0; t < 9; ++t) {
            const int kh = t / 3, kw = t % 3;
            const short8 bhi = rhi[(rr + kh) % 3][kw];
            const short8 blo = *(const short8*)(base + (rr + kh) * ROWB + offL[kw]);
            acc = __builtin_amdgcn_mfma_f32_32x32x16_bf16(whi[t], bhi, acc, 0, 0, 0);
            acc = __builtin_amdgcn_mfma_f32_32x32x16_bf16(wlo[t], bhi, acc, 0, 0, 0);
            acc = __builtin_amdgcn_mfma_f32_32x32x16_bf16(whi[t], blo, acc, 0, 0, 0);
        }
        acc = __builtin_amdgcn_mfma_f32_32x32x16_bf16(whi[9], ones, acc, 0, 0, 0);

        // min over 16 in-lane oc rows (tree), then partner half-wave
        float m0 = fminf(acc[0],  acc[1]),  m1 = fminf(acc[2],  acc[3]);
        float m2 = fminf(acc[4],  acc[5]),  m3 = fminf(acc[6],  acc[7]);
        float m4 = fminf(acc[8],  acc[9]),  m5 = fminf(acc[10], acc[11]);
        float m6 = fminf(acc[12], acc[13]), m7 = fminf(acc[14], acc[15]);
        m0 = fminf(m0, m1); m2 = fminf(m2, m3); m4 = fminf(m4, m5); m6 = fminf(m6, m7);
        m0 = fminf(m0, m2); m4 = fminf(m4, m6);
        float mv = fminf(m0, m4);
        mv = fminf(mv, __shfl_xor(mv, 32, 64));
        if (lane < 32) comb[oct][rbase + rr][lane] = mv;
    }

    __syncthreads();

    // ---- combine oc-tiles, tanh(tanh()), masked store ----
    for (int i = tid; i < TH * TW; i += 256) {
        const int row  = i >> 5;
        const int colp = i & 31;
        const int oh = oh0 + row;
        const int ow = ow0 + colp;
        if (oh < OHH && ow < OWW) {
            out[((size_t)n * OHH + oh) * OWW + ow] =
                tanh2_fast(fminf(comb[0][row][colp], comb[1][row][colp]));
        }
    }
}

extern "C" void kernel_launch(void* const* d_in, const int* in_sizes, int n_in,
                              void* d_out, int out_size, void* d_ws, size_t ws_size,
                              hipStream_t stream)
{
    const float* x = (const float*)d_in[0];
    const float* w = (const float*)d_in[1];
    const float* b = (const float*)d_in[2];
    float* out     = (float*)d_out;
    short8* ws     = (short8*)d_ws;   // 38912 B used

    split_weights<<<1, 128, 0, stream>>>(w, b, ws);
    dim3 grid(22 * 8, NB);   // 22 row-tiles * 8 col-tiles, 32 batches
    conv_min_tanh_mfma4<<<grid, 256, 0, stream>>>(x, ws, out);
}

// Round 8
// 251.549 us; speedup vs baseline: 2.7000x; 1.0153x over previous
//
#include <hip/hip_runtime.h>
#include <math.h>

// Fused Conv2d(16->64,3x3,VALID)+bias -> min(oc) -> tanh(tanh()).
// R8: 2-term weight-split MFMA: y = bf16(x)*wh + bf16(x)*wl (+bias tap).
//   - MFMA/rr 29->19 (content 49->32 us), B-reads/rr 18->9: breaks the
//     R6/R7 LDS-read<->MFMA 1:1 co-saturation (both pipes ~48 us).
//   - LDS halves (no x-lo): 2 cols packed per 64B cell, same conflict-free
//     read geometry; 23.7KB/block -> 5-6 resident blocks/CU for overlap.
//   - Accuracy: adds |(x-bf16(x))*w| ~ 6e-4 RMS pre-activation; fallback
//     if absmax fails = 3-term in this same structure.

#define IN_C  16
#define OUT_C 64
#define HH    256
#define WW    256
#define OHH   254
#define OWW   254
#define NB    32

#define TH 16       // output rows per block
#define TW 32       // output cols per block (= MFMA N)
#define HR (TH + 2) // 18 halo rows staged
#define HC 34       // halo cols staged
#define NCP 17      // 64B cells per row (2 cols packed per cell)
#define ROWB (NCP * 64)   // 1088 B per LDS row

typedef __attribute__((ext_vector_type(8)))  short short8;    // 8 bf16
typedef __attribute__((ext_vector_type(16))) float floatx16;  // 16 f32 acc

__device__ __forceinline__ unsigned short f2bf(float f) {   // RNE
    unsigned u = __float_as_uint(f);
    u = u + 0x7FFFu + ((u >> 16) & 1u);
    return (unsigned short)(u >> 16);
}
__device__ __forceinline__ float bf2f(unsigned short h) {
    return __uint_as_float(((unsigned)h) << 16);
}

// LDS cell(r, cp) = 64B = 4 slots of 16B. Logical slot for column colh
// (cp = colh>>1), channel block cblk (0: c0-7, 1: c8-15):
//   s = (colh&1)*2 + cblk.  Physical slot = s ^ swz2(cp), period-16 XOR
// so any 32-consecutive-colh b128 read window is conflict-free (proven
// geometry from R4/R6: 64 lanes hit 64 distinct 16B granules in a
// contiguous ~1KB region).
__device__ __forceinline__ int swz2(int cp) {
    return (cp ^ (cp >> 2)) & 3;
}
__device__ __forceinline__ int cell_addr(int r, int colh, int cblk) {
    const int cp = colh >> 1;
    const int s  = ((colh & 1) << 1) + cblk;
    return r * ROWB + cp * 64 + ((s ^ swz2(cp)) << 4);
}

// tanh(tanh(v)) via fast exp; saturates correctly at +-large.
__device__ __forceinline__ float tanh2_fast(float v) {
    const float e1 = __expf(2.0f * v);
    const float t1 = 1.0f - 2.0f / (e1 + 1.0f);
    const float e2 = __expf(2.0f * t1);
    return 1.0f - 2.0f / (e2 + 1.0f);
}

// ---- pre-kernel: split weights/bias to MFMA-fragment order in d_ws ----
// HI frags: ws[(oct*10 + t)*64 + lane], t=0..8 taps, t=9 = bias tap.
// LO frags: ws[1280 + (oct*9 + t)*64 + lane], t=0..8.
// Lane layout (A-operand, 32x32x16): oc = oct*32 + (lane&31), c = 8*(lane>>5)+j.
__global__ void split_weights(const float* __restrict__ w,
                              const float* __restrict__ bias,
                              short8* __restrict__ ws)
{
    const int tid = threadIdx.x;
    if (tid >= 128) return;
    const int oct  = tid >> 6;
    const int lane = tid & 63;
    const int oc   = oct * 32 + (lane & 31);
    const int cb   = (lane >> 5) * 8;
#pragma unroll
    for (int t = 0; t < 9; ++t) {
        const int kh = t / 3, kw = t % 3;
        short8 hi, lo;
#pragma unroll
        for (int j = 0; j < 8; ++j) {
            const float wv = w[((oc * IN_C + cb + j) * 3 + kh) * 3 + kw];
            const unsigned short h = f2bf(wv);
            hi[j] = (short)h;
            lo[j] = (short)f2bf(wv - bf2f(h));
        }
        ws[(oct * 10 + t) * 64 + lane]        = hi;
        ws[1280 + (oct * 9 + t) * 64 + lane]  = lo;
    }
    short8 wb = {};
    if (lane < 32) {
        const float bv = bias[oc];
        const unsigned short h = f2bf(bv);
        wb[0] = (short)h;
        wb[1] = (short)f2bf(bv - bf2f(h));
    }
    ws[(oct * 10 + 9) * 64 + lane] = wb;
}

__global__ __launch_bounds__(256, 4)
void conv_min_tanh_mfma5(const float* __restrict__ x,
                         const short8* __restrict__ ws,
                         float* __restrict__ out)
{
    __shared__ __align__(64) unsigned char lds_x[HR * ROWB];   // 19584 B
    __shared__ float comb[2][TH][TW];                          // 4096 B

    const int tid  = threadIdx.x;
    const int lane = tid & 63;
    const int wave = tid >> 6;

    const int bx      = blockIdx.x;      // 0..127
    const int coltile = bx & 7;
    const int rowtile = bx >> 3;         // 0..15
    const int n       = blockIdx.y;
    const int oh0     = rowtile * TH;
    const int ow0     = coltile * TW;

    const float* xn = x + (size_t)n * IN_C * HH * WW;

    // ---- weight fragments from d_ws (L2-resident, fragment-ordered) ----
    const int oct   = wave & 1;                  // waves 0,1: oc 0-31 / 32-63
    const int rbase = (wave >> 1) * (TH / 2);    // waves 0,1: rows 0-7; 2,3: 8-15
    short8 whi[10], wlo[9];
#pragma unroll
    for (int t = 0; t < 10; ++t) whi[t] = ws[(oct * 10 + t) * 64 + lane];
#pragma unroll
    for (int t = 0; t < 9; ++t)  wlo[t] = ws[1280 + (oct * 9 + t) * 64 + lane];
    short8 ones = {};
    if (lane < 32) { ones[0] = (short)0x3F80; ones[1] = (short)0x3F80; }

    // ---- stage x tile: per (r,colh) load 16 channels, RNE-convert to
    // bf16 (single term), 2 conflict-free ds_write_b128 per item ----
    for (int i = tid; i < HR * HC; i += 256) {
        const int r    = i / HC;
        const int colh = i - r * HC;
        const int gr = min(oh0 + r, HH - 1);      // clamp bottom halo
        const int gc = min(ow0 + colh, WW - 1);   // clamp right halo
        const float* xp = xn + gr * WW + gc;
        float v[IN_C];
#pragma unroll
        for (int c = 0; c < IN_C; ++c) v[c] = xp[c * (HH * WW)];
        short8 s0, s1;
#pragma unroll
        for (int j = 0; j < 8; ++j) {
            s0[j] = (short)f2bf(v[j]);
            s1[j] = (short)f2bf(v[j + 8]);
        }
        *(short8*)(lds_x + cell_addr(r, colh, 0)) = s0;
        *(short8*)(lds_x + cell_addr(r, colh, 1)) = s1;
    }

    __syncthreads();

    // ---- MFMA loop: per tap ONE B read (xh), TWO MFMAs (wh, wl).
    // Read addr = (rl+kh)*ROWB + off2[kw]; kh*ROWB folds to immediates.
    const int colb = lane & 31;
    const int cblk = lane >> 5;
    int off2[3];
#pragma unroll
    for (int kw = 0; kw < 3; ++kw)
        off2[kw] = cell_addr(0, colb + kw, cblk);

    for (int rr = 0; rr < TH / 2; ++rr) {
        const int rl = rbase + rr;
        floatx16 acc = {};
#pragma unroll
        for (int t = 0; t < 9; ++t) {
            const int kh = t / 3, kw = t % 3;
            const short8 bhi =
                *(const short8*)(lds_x + (rl + kh) * ROWB + off2[kw]);
            acc = __builtin_amdgcn_mfma_f32_32x32x16_bf16(whi[t], bhi, acc, 0, 0, 0);
            acc = __builtin_amdgcn_mfma_f32_32x32x16_bf16(wlo[t], bhi, acc, 0, 0, 0);
        }
        acc = __builtin_amdgcn_mfma_f32_32x32x16_bf16(whi[9], ones, acc, 0, 0, 0);

        // min over 16 in-lane oc rows (tree), then partner half-wave
        float m0 = fminf(acc[0],  acc[1]),  m1 = fminf(acc[2],  acc[3]);
        float m2 = fminf(acc[4],  acc[5]),  m3 = fminf(acc[6],  acc[7]);
        float m4 = fminf(acc[8],  acc[9]),  m5 = fminf(acc[10], acc[11]);
        float m6 = fminf(acc[12], acc[13]), m7 = fminf(acc[14], acc[15]);
        m0 = fminf(m0, m1); m2 = fminf(m2, m3); m4 = fminf(m4, m5); m6 = fminf(m6, m7);
        m0 = fminf(m0, m2); m4 = fminf(m4, m6);
        float mv = fminf(m0, m4);
        mv = fminf(mv, __shfl_xor(mv, 32, 64));
        if (lane < 32) comb[oct][rl][lane] = mv;
    }

    __syncthreads();

    // ---- combine oc-tiles, tanh(tanh()), masked store ----
    for (int i = tid; i < TH * TW; i += 256) {
        const int row  = i >> 5;
        const int colp = i & 31;
        const int oh = oh0 + row;
        const int ow = ow0 + colp;
        if (oh < OHH && ow < OWW) {
            out[((size_t)n * OHH + oh) * OWW + ow] =
                tanh2_fast(fminf(comb[0][row][colp], comb[1][row][colp]));
        }
    }
}

extern "C" void kernel_launch(void* const* d_in, const int* in_sizes, int n_in,
                              void* d_out, int out_size, void* d_ws, size_t ws_size,
                              hipStream_t stream)
{
    const float* x = (const float*)d_in[0];
    const float* w = (const float*)d_in[1];
    const float* b = (const float*)d_in[2];
    float* out     = (float*)d_out;
    short8* ws     = (short8*)d_ws;   // 38912 B used

    split_weights<<<1, 128, 0, stream>>>(w, b, ws);
    dim3 grid(16 * 8, NB);   // 16 row-tiles * 8 col-tiles, 32 batches
    conv_min_tanh_mfma5<<<grid, 256, 0, stream>>>(x, ws, out);
}

// Round 9
// 231.618 us; speedup vs baseline: 2.9323x; 1.0861x over previous
//
#include <hip/hip_runtime.h>
#include <math.h>

// Fused Conv2d(16->64,3x3,VALID)+bias -> min(oc) -> tanh(tanh()).
// R9: identical to R8's 2-term weight-split structure; ONLY change is
// __launch_bounds__(256,4) -> (256,3). R8's bound pushed the allocator to
// the 64-VGPR tier -> weight frags (76 VGPR) spilled to scratch (WRITE_SIZE
// 9.6->50 MB, MfmaUtil 30%). (256,3) is the R6-proven no-spill config.
// 2-term math: y = bf16(x)*wh + bf16(x)*wl (+bias tap), absmax unchanged.

#define IN_C  16
#define OUT_C 64
#define HH    256
#define WW    256
#define OHH   254
#define OWW   254
#define NB    32

#define TH 16       // output rows per block
#define TW 32       // output cols per block (= MFMA N)
#define HR (TH + 2) // 18 halo rows staged
#define HC 34       // halo cols staged
#define NCP 17      // 64B cells per row (2 cols packed per cell)
#define ROWB (NCP * 64)   // 1088 B per LDS row

typedef __attribute__((ext_vector_type(8)))  short short8;    // 8 bf16
typedef __attribute__((ext_vector_type(16))) float floatx16;  // 16 f32 acc

__device__ __forceinline__ unsigned short f2bf(float f) {   // RNE
    unsigned u = __float_as_uint(f);
    u = u + 0x7FFFu + ((u >> 16) & 1u);
    return (unsigned short)(u >> 16);
}
__device__ __forceinline__ float bf2f(unsigned short h) {
    return __uint_as_float(((unsigned)h) << 16);
}

// LDS cell(r, cp) = 64B = 4 slots of 16B. Logical slot for column colh
// (cp = colh>>1), channel block cblk (0: c0-7, 1: c8-15):
//   s = (colh&1)*2 + cblk.  Physical slot = s ^ swz2(cp), period-16 XOR
// so any 32-consecutive-colh b128 read window is conflict-free.
__device__ __forceinline__ int swz2(int cp) {
    return (cp ^ (cp >> 2)) & 3;
}
__device__ __forceinline__ int cell_addr(int r, int colh, int cblk) {
    const int cp = colh >> 1;
    const int s  = ((colh & 1) << 1) + cblk;
    return r * ROWB + cp * 64 + ((s ^ swz2(cp)) << 4);
}

// tanh(tanh(v)) via fast exp; saturates correctly at +-large.
__device__ __forceinline__ float tanh2_fast(float v) {
    const float e1 = __expf(2.0f * v);
    const float t1 = 1.0f - 2.0f / (e1 + 1.0f);
    const float e2 = __expf(2.0f * t1);
    return 1.0f - 2.0f / (e2 + 1.0f);
}

// ---- pre-kernel: split weights/bias to MFMA-fragment order in d_ws ----
// HI frags: ws[(oct*10 + t)*64 + lane], t=0..8 taps, t=9 = bias tap.
// LO frags: ws[1280 + (oct*9 + t)*64 + lane], t=0..8.
// Lane layout (A-operand, 32x32x16): oc = oct*32 + (lane&31), c = 8*(lane>>5)+j.
__global__ void split_weights(const float* __restrict__ w,
                              const float* __restrict__ bias,
                              short8* __restrict__ ws)
{
    const int tid = threadIdx.x;
    if (tid >= 128) return;
    const int oct  = tid >> 6;
    const int lane = tid & 63;
    const int oc   = oct * 32 + (lane & 31);
    const int cb   = (lane >> 5) * 8;
#pragma unroll
    for (int t = 0; t < 9; ++t) {
        const int kh = t / 3, kw = t % 3;
        short8 hi, lo;
#pragma unroll
        for (int j = 0; j < 8; ++j) {
            const float wv = w[((oc * IN_C + cb + j) * 3 + kh) * 3 + kw];
            const unsigned short h = f2bf(wv);
            hi[j] = (short)h;
            lo[j] = (short)f2bf(wv - bf2f(h));
        }
        ws[(oct * 10 + t) * 64 + lane]        = hi;
        ws[1280 + (oct * 9 + t) * 64 + lane]  = lo;
    }
    short8 wb = {};
    if (lane < 32) {
        const float bv = bias[oc];
        const unsigned short h = f2bf(bv);
        wb[0] = (short)h;
        wb[1] = (short)f2bf(bv - bf2f(h));
    }
    ws[(oct * 10 + 9) * 64 + lane] = wb;
}

__global__ __launch_bounds__(256, 3)
void conv_min_tanh_mfma6(const float* __restrict__ x,
                         const short8* __restrict__ ws,
                         float* __restrict__ out)
{
    __shared__ __align__(64) unsigned char lds_x[HR * ROWB];   // 19584 B
    __shared__ float comb[2][TH][TW];                          // 4096 B

    const int tid  = threadIdx.x;
    const int lane = tid & 63;
    const int wave = tid >> 6;

    const int bx      = blockIdx.x;      // 0..127
    const int coltile = bx & 7;
    const int rowtile = bx >> 3;         // 0..15
    const int n       = blockIdx.y;
    const int oh0     = rowtile * TH;
    const int ow0     = coltile * TW;

    const float* xn = x + (size_t)n * IN_C * HH * WW;

    // ---- weight fragments from d_ws (L2-resident, fragment-ordered) ----
    const int oct   = wave & 1;                  // waves 0,1: oc 0-31 / 32-63
    const int rbase = (wave >> 1) * (TH / 2);    // waves 0,1: rows 0-7; 2,3: 8-15
    short8 whi[10], wlo[9];
#pragma unroll
    for (int t = 0; t < 10; ++t) whi[t] = ws[(oct * 10 + t) * 64 + lane];
#pragma unroll
    for (int t = 0; t < 9; ++t)  wlo[t] = ws[1280 + (oct * 9 + t) * 64 + lane];
    short8 ones = {};
    if (lane < 32) { ones[0] = (short)0x3F80; ones[1] = (short)0x3F80; }

    // ---- stage x tile: per (r,colh) load 16 channels, RNE-convert to
    // bf16 (single term), 2 conflict-free ds_write_b128 per item ----
    for (int i = tid; i < HR * HC; i += 256) {
        const int r    = i / HC;
        const int colh = i - r * HC;
        const int gr = min(oh0 + r, HH - 1);      // clamp bottom halo
        const int gc = min(ow0 + colh, WW - 1);   // clamp right halo
        const float* xp = xn + gr * WW + gc;
        float v[IN_C];
#pragma unroll
        for (int c = 0; c < IN_C; ++c) v[c] = xp[c * (HH * WW)];
        short8 s0, s1;
#pragma unroll
        for (int j = 0; j < 8; ++j) {
            s0[j] = (short)f2bf(v[j]);
            s1[j] = (short)f2bf(v[j + 8]);
        }
        *(short8*)(lds_x + cell_addr(r, colh, 0)) = s0;
        *(short8*)(lds_x + cell_addr(r, colh, 1)) = s1;
    }

    __syncthreads();

    // ---- MFMA loop: per tap ONE B read (xh), TWO MFMAs (wh, wl).
    // Read addr = (rl+kh)*ROWB + off2[kw]; kh*ROWB folds to immediates.
    const int colb = lane & 31;
    const int cblk = lane >> 5;
    int off2[3];
#pragma unroll
    for (int kw = 0; kw < 3; ++kw)
        off2[kw] = cell_addr(0, colb + kw, cblk);

    for (int rr = 0; rr < TH / 2; ++rr) {
        const int rl = rbase + rr;
        floatx16 acc = {};
#pragma unroll
        for (int t = 0; t < 9; ++t) {
            const int kh = t / 3, kw = t % 3;
            const short8 bhi =
                *(const short8*)(lds_x + (rl + kh) * ROWB + off2[kw]);
            acc = __builtin_amdgcn_mfma_f32_32x32x16_bf16(whi[t], bhi, acc, 0, 0, 0);
            acc = __builtin_amdgcn_mfma_f32_32x32x16_bf16(wlo[t], bhi, acc, 0, 0, 0);
        }
        acc = __builtin_amdgcn_mfma_f32_32x32x16_bf16(whi[9], ones, acc, 0, 0, 0);

        // min over 16 in-lane oc rows (tree), then partner half-wave
        float m0 = fminf(acc[0],  acc[1]),  m1 = fminf(acc[2],  acc[3]);
        float m2 = fminf(acc[4],  acc[5]),  m3 = fminf(acc[6],  acc[7]);
        float m4 = fminf(acc[8],  acc[9]),  m5 = fminf(acc[10], acc[11]);
        float m6 = fminf(acc[12], acc[13]), m7 = fminf(acc[14], acc[15]);
        m0 = fminf(m0, m1); m2 = fminf(m2, m3); m4 = fminf(m4, m5); m6 = fminf(m6, m7);
        m0 = fminf(m0, m2); m4 = fminf(m4, m6);
        float mv = fminf(m0, m4);
        mv = fminf(mv, __shfl_xor(mv, 32, 64));
        if (lane < 32) comb[oct][rl][lane] = mv;
    }

    __syncthreads();

    // ---- combine oc-tiles, tanh(tanh()), masked store ----
    for (int i = tid; i < TH * TW; i += 256) {
        const int row  = i >> 5;
        const int colp = i & 31;
        const int oh = oh0 + row;
        const int ow = ow0 + colp;
        if (oh < OHH && ow < OWW) {
            out[((size_t)n * OHH + oh) * OWW + ow] =
                tanh2_fast(fminf(comb[0][row][colp], comb[1][row][colp]));
        }
    }
}

extern "C" void kernel_launch(void* const* d_in, const int* in_sizes, int n_in,
                              void* d_out, int out_size, void* d_ws, size_t ws_size,
                              hipStream_t stream)
{
    const float* x = (const float*)d_in[0];
    const float* w = (const float*)d_in[1];
    const float* b = (const float*)d_in[2];
    float* out     = (float*)d_out;
    short8* ws     = (short8*)d_ws;   // 38912 B used

    split_weights<<<1, 128, 0, stream>>>(w, b, ws);
    dim3 grid(16 * 8, NB);   // 16 row-tiles * 8 col-tiles, 32 batches
    conv_min_tanh_mfma6<<<grid, 256, 0, stream>>>(x, ws, out);
}